// Round 14
// baseline (808.453 us; speedup 1.0000x reference)
//
#include <hip/hip_runtime.h>
#include <hip/hip_bf16.h>
#include <math.h>

// ---------------------------------------------------------------------------
// CapsNet forward. R14 = R13 + two changes:
//  - conv2 v3: waves re-blocked as 4 M-groups{3,2,2,2 tiles} x 2 oc-halves
//    (2 B-frags/wave). A-fragment LDS reads halve (72->36 b128/step) since
//    each M-tile is read by 2 waves not 4 -> conflicts (5.6e7 = ~91us/CU,
//    35% of conv2) should halve.
//  - k_prep: wrep+rrep+conv1 merged into one dispatch (independent work;
//    overlap + 2 fewer gaps).
// ---------------------------------------------------------------------------

typedef __attribute__((ext_vector_type(8))) short bf16x8;
typedef __attribute__((ext_vector_type(4))) float f32x4;

__device__ __forceinline__ void gl16(const void* g, void* l) {
  __builtin_amdgcn_global_load_lds((const __attribute__((address_space(1))) void*)g,
                                   (__attribute__((address_space(3))) void*)l,
                                   16, 0, 0);
}

// ==== k_prep: [0,2688) wrep | [2688,2868) rrep | [2868,3892) conv1 =========
// wrep: pw[oc][ic][81] -> wGp[step672][ocq4][oc64][32hi|32lo|8z]
// rrep: rw[o][i][c][d] -> rwT[o][c*16+d][i]
// conv1: x -> hTg[img][ch][(x*41+y*2+half) chunk][8 bf16]
__global__ __launch_bounds__(256) void k_prep(
    const float* __restrict__ pw, __hip_bfloat16* __restrict__ wGp,
    const float* __restrict__ rw, float* __restrict__ rwT,
    const float* __restrict__ x, const float* __restrict__ c1w,
    const float* __restrict__ c1b, __hip_bfloat16* __restrict__ hT) {
  __shared__ __attribute__((aligned(16))) char smem[44480];
  const int bid = blockIdx.x;
  const int t = threadIdx.x;
  if (bid < 2688) {                                 // ---- wrep ----
    const int s = bid >> 2, ocq = bid & 3;          // s in [0,672)
    const int ch = s / 21, tq = s - ch * 21;
    __hip_bfloat16* outp = wGp + ((size_t)s * 4 + ocq) * 4608;
    for (int e = t; e < 2048; e += 256) {
      const int ocl = e >> 5, k = e & 31;
      const int tapl = k >> 3, icl = k & 7;
      const int tap = tq * 4 + tapl, ic = ch * 8 + icl;
      const int oc = ocq * 64 + ocl;
      const float v = (tap < 81) ? pw[((size_t)oc * 256 + ic) * 81 + tap] : 0.f;
      const __hip_bfloat16 hi = __float2bfloat16(v);
      const __hip_bfloat16 lo = __float2bfloat16(v - __bfloat162float(hi));
      outp[ocl * 72 + k] = hi;
      outp[ocl * 72 + 32 + k] = lo;
    }
    for (int e = t; e < 512; e += 256) {
      const int ocl = e >> 3, j = e & 7;
      outp[ocl * 72 + 64 + j] = __float2bfloat16(0.f);
    }
  } else if (bid < 2868) {                          // ---- rrep ----
    float* tile = (float*)smem;                     // 64*129 floats (33KB)
    const int bb = bid - 2688;
    const int o = bb / 18, ig = bb % 18;
    for (int idx = t; idx < 64 * 128; idx += 256) {
      const int i = idx >> 7, cd = idx & 127;
      tile[i * 129 + cd] = rw[((size_t)o * 1152 + ig * 64 + i) * 128 + cd];
    }
    __syncthreads();
    for (int idx = t; idx < 64 * 128; idx += 256) {
      const int cd = idx >> 6, il = idx & 63;
      rwT[((size_t)o * 128 + cd) * 1152 + ig * 64 + il] = tile[il * 129 + cd];
    }
  } else {                                          // ---- conv1 ----
    const int bb = bid - 2868;
    const int img = bb >> 2, ocq = bb & 3;          // 64 oc per block
    float* xs = (float*)smem;                       // 784 f
    float* ws = xs + 784;                           // 5184 f
    __hip_bfloat16* tile = (__hip_bfloat16*)(ws + 5184);  // 8*1288 bf16
    const float4* xg = (const float4*)(x + (size_t)img * 784);
    if (t < 196) ((float4*)xs)[t] = xg[t];
    const float4* wg = (const float4*)(c1w + (size_t)ocq * 64 * 81);
    for (int i = t; i < 1296; i += 256) ((float4*)ws)[i] = wg[i];
    __syncthreads();
    const int ocl = t & 63, rowg = t >> 6;          // wave = rowg
    const int oc = ocq * 64 + ocl;
    const int chl = ocl >> 3, icl = ocl & 7;
    const float bv = c1b[oc];
    __hip_bfloat16* hb = hT + ((size_t)img * 32 + ocq * 8) * 6560;
#pragma unroll 1
    for (int it = 0; it < 5; it++) {
      const int r = it * 4 + rowg;                  // y
      float acc[20];
#pragma unroll
      for (int p = 0; p < 20; p++) acc[p] = bv;
#pragma unroll
      for (int ky = 0; ky < 9; ky++) {
        float xr[28];
        const float* xrow = &xs[(r + ky) * 28];
#pragma unroll
        for (int q = 0; q < 7; q++) ((float4*)xr)[q] = ((const float4*)xrow)[q];
        float wr[9];
#pragma unroll
        for (int i = 0; i < 9; i++) wr[i] = ws[ocl * 81 + ky * 9 + i];
#pragma unroll
        for (int kx = 0; kx < 9; kx++)
#pragma unroll
          for (int p = 0; p < 20; p++)
            acc[p] = fmaf(wr[kx], xr[p + kx], acc[p]);
      }
#pragma unroll
      for (int p = 0; p < 20; p++) {                // p = x
        const float v = fmaxf(acc[p], 0.f);
        const __hip_bfloat16 hi = __float2bfloat16(v);
        const __hip_bfloat16 lo = __float2bfloat16(v - __bfloat162float(hi));
        tile[chl * 1288 + (p * 8 + rowg * 2) * 8 + icl] = hi;
        tile[chl * 1288 + (p * 8 + rowg * 2 + 1) * 8 + icl] = lo;
      }
      __syncthreads();
#pragma unroll
      for (int q = 0; q < 5; q++) {                 // 1280 16B chunks
        const int idx = q * 256 + t;
        const int c2 = idx / 160, rem = idx - c2 * 160;
        const int xx = rem >> 3, j = rem & 7;
        const float4 vdat = *(const float4*)&tile[c2 * 1288 + rem * 8];
        *(float4*)(hb + (size_t)c2 * 6560 + (size_t)(xx * 41 + it * 8 + j) * 8) = vdat;
      }
      __syncthreads();
    }
  }
}

// ====== conv2 MFMA v3: pq[kq][img][px36][oc256] partial over 16 ch =========
// 8 waves = 4 M-groups {3,2,2,2 tiles} x 2 oc-halves (2 B-frags each).
#define HT_B 52480              // 3280 chunks x 16B  (4 img x 820)
#define PQ_F 2359296
__global__ __launch_bounds__(512) void k_conv2(
    const __hip_bfloat16* __restrict__ hTg,    // [chunk img][32ch][820ch][8]
    const __hip_bfloat16* __restrict__ wGp,    // [672][4ocq][4608B] (+1 pad step)
    float* __restrict__ pq, int c0) {
  __shared__ char hT[HT_B];
  const int bid = blockIdx.x;
  int ig, ocq, kq;
  if (gridDim.x == 512) {       // XCD swizzle: ocq sharers keep bid%8
    ig = (bid & 7) | (((bid >> 5) & 7) << 3);
    ocq = (bid >> 3) & 3;
    kq = bid >> 8;
  } else {
    ig = bid >> 3;
    ocq = (bid >> 1) & 3;
    kq = bid & 1;
  }
  const int t = threadIdx.x;
  const int w = t >> 6, lane = t & 63;
  const int lquad = lane >> 4, lrow = lane & 15;
  const int Mg = w >> 1, oc2 = w & 1;
  const int nt = (Mg == 0) ? 3 : 2;                 // tiles {3,2,2,2}
  const int mtb = (Mg == 0) ? 0 : (2 * Mg + 1);     // bases {0,3,5,7}
  int abase[3];
#pragma unroll
  for (int i = 0; i < 3; i++) {
    int mt = mtb + i;
    if (i >= nt) mt = 0;
    const int m = mt * 16 + lrow;
    const int img = m / 36, px = m - img * 36;
    const int oy = px / 6, ox = px - oy * 6;
    abase[i] = img * 13120 + ox * 1312 + oy * 64;   // bytes in hT
  }
  f32x4 acc[3][2];
#pragma unroll
  for (int i = 0; i < 3; i++) {
    acc[i][0] = (f32x4){0.f, 0.f, 0.f, 0.f};
    acc[i][1] = (f32x4){0.f, 0.f, 0.f, 0.f};
  }
  const char* hgc = (const char*)hTg;
  // 2 B-fragment rows per lane: oc = ocq*64 + oc2*32 + {0,16} + lrow
  const char* wp = (const char*)wGp + ((size_t)(kq * 336) * 4 + ocq) * 4608 +
                   (oc2 * 32 + lrow) * 144 + lquad * 16;
  bf16x8 bh0 = *(const bf16x8*)wp;
  bf16x8 bl0 = *(const bf16x8*)(wp + 64);
  bf16x8 bh1 = *(const bf16x8*)(wp + 2304);
  bf16x8 bl1 = *(const bf16x8*)(wp + 2368);
  wp += 18432;
#pragma unroll 1
  for (int chl = 0; chl < 16; chl++) {
    const int ch = kq * 16 + chl;
    const char* hch = hgc + ((size_t)(ig * 128) + ch) * 13120;
#pragma unroll
    for (int rr = 0; rr < 6; rr++) {
      const int idx = t + rr * 512;
      const int j = idx / 820, r = idx - j * 820;
      gl16(hch + (size_t)j * 419840 + r * 16, hT + rr * 8192 + w * 1024);
    }
    if (t < 208) {
      const int idx = 3072 + t;
      const int j = idx / 820, r = idx - j * 820;
      gl16(hch + (size_t)j * 419840 + r * 16, hT + 49152 + w * 1024);
    }
    __syncthreads();
#pragma unroll 1
    for (int tq = 0; tq < 21; tq++) {
      const bf16x8 nh0 = *(const bf16x8*)wp;        // prefetch next step's W
      const bf16x8 nl0 = *(const bf16x8*)(wp + 64);
      const bf16x8 nh1 = *(const bf16x8*)(wp + 2304);
      const bf16x8 nl1 = *(const bf16x8*)(wp + 2368);
      wp += 18432;
      const int tt = tq * 4 + lquad;                // this quad's tap
      const int ky = tt / 9, kx = tt - ky * 9;
      const int toff = kx * 656 + ky * 32;          // (kx*41 + ky*2) chunks
      bf16x8 ah[3];
#pragma unroll
      for (int i = 0; i < 3; i++)
        if (i < nt) ah[i] = *(const bf16x8*)(hT + abase[i] + toff);
#pragma unroll
      for (int i = 0; i < 3; i++)
        if (i < nt) acc[i][0] = __builtin_amdgcn_mfma_f32_16x16x32_bf16(ah[i], bh0, acc[i][0], 0, 0, 0);
#pragma unroll
      for (int i = 0; i < 3; i++)
        if (i < nt) acc[i][1] = __builtin_amdgcn_mfma_f32_16x16x32_bf16(ah[i], bh1, acc[i][1], 0, 0, 0);
#pragma unroll
      for (int i = 0; i < 3; i++)
        if (i < nt) acc[i][0] = __builtin_amdgcn_mfma_f32_16x16x32_bf16(ah[i], bl0, acc[i][0], 0, 0, 0);
#pragma unroll
      for (int i = 0; i < 3; i++)
        if (i < nt) acc[i][1] = __builtin_amdgcn_mfma_f32_16x16x32_bf16(ah[i], bl1, acc[i][1], 0, 0, 0);
      bf16x8 al[3];
#pragma unroll
      for (int i = 0; i < 3; i++)
        if (i < nt) al[i] = *(const bf16x8*)(hT + abase[i] + toff + 16);
#pragma unroll
      for (int i = 0; i < 3; i++)
        if (i < nt) acc[i][0] = __builtin_amdgcn_mfma_f32_16x16x32_bf16(al[i], bh0, acc[i][0], 0, 0, 0);
#pragma unroll
      for (int i = 0; i < 3; i++)
        if (i < nt) acc[i][1] = __builtin_amdgcn_mfma_f32_16x16x32_bf16(al[i], bh1, acc[i][1], 0, 0, 0);
      bh0 = nh0; bl0 = nl0; bh1 = nh1; bl1 = nl1;
    }
    __syncthreads();                                // hT reuse fence
  }
  float* pblk = pq + (size_t)kq * PQ_F;
#pragma unroll
  for (int i = 0; i < 3; i++) {
    if (i < nt) {
#pragma unroll
      for (int f = 0; f < 2; f++) {
        const int oc = ocq * 64 + oc2 * 32 + f * 16 + lrow;
#pragma unroll
        for (int r = 0; r < 4; r++) {
          const int m = (mtb + i) * 16 + lquad * 4 + r;   // D row = quad*4+reg
          const int img = m / 36, px = m - img * 36;
          pblk[((size_t)(c0 + ig * 4 + img) * 36 + px) * 256 + oc] = acc[i][f][r];
        }
      }
    }
  }
}

// ===== squash v2: block/b, LDS-staged coalesced ============================
__global__ __launch_bounds__(256) void k_squash(const float* __restrict__ pq,
                                                const float* __restrict__ bias,
                                                float* __restrict__ u) {
  const int b = blockIdx.x;
  __shared__ float ps[36 * 257];
  const int t = threadIdx.x;
  const float4* s0 = (const float4*)(pq + (size_t)b * 9216);
  const float4* s1 = (const float4*)(pq + (size_t)PQ_F + (size_t)b * 9216);
#pragma unroll
  for (int q = 0; q < 9; q++) {                     // 2304 float4, coalesced
    const int idx = q * 256 + t;
    const float4 a = s0[idx], c = s1[idx];
    const int px = idx >> 6, oc = (idx & 63) * 4;
    float* dst = &ps[px * 257 + oc];
    dst[0] = a.x + c.x; dst[1] = a.y + c.y;
    dst[2] = a.z + c.z; dst[3] = a.w + c.w;
  }
  __syncthreads();
#pragma unroll
  for (int rr = 0; rr < 5; rr++) {
    const int i = rr * 256 + t;
    if (i < 1152) {
      const int cp = i / 36, px = i - cp * 36;
      float s[8], sq = 0.f;
#pragma unroll
      for (int d = 0; d < 8; d++) {
        s[d] = ps[px * 257 + d * 32 + cp] + bias[d * 32 + cp];
        sq = fmaf(s[d], s[d], sq);
      }
      const float scale = sq / ((1.f + sq) * sqrtf(sq));
      float o[8];
#pragma unroll
      for (int d = 0; d < 8; d++) o[d] = s[d] * scale;
      float* ub = u + ((size_t)b * 1152 + i) * 8;
      ((float4*)ub)[0] = ((float4*)o)[0];
      ((float4*)ub)[1] = ((float4*)o)[1];
    }
  }
}

// ======================= routing by agreement ==============================
__device__ __forceinline__ float wsum(float v) {
#pragma unroll
  for (int o = 32; o > 0; o >>= 1) v += __shfl_xor(v, o, 64);
  return v;
}
__device__ __forceinline__ float wmaxr(float v) {
#pragma unroll
  for (int o = 32; o > 0; o >>= 1) v = fmaxf(v, __shfl_xor(v, o, 64));
  return v;
}

// route v5: 2 imgs per block, priors fp32 in LDS (144KB), rwT read once.
__global__ __launch_bounds__(512) void k_route(const float* __restrict__ u,
                                               const float* __restrict__ rwT,
                                               float* __restrict__ vecs) {
  const int bid = blockIdx.x;
  int o, bp;
  if (bid < 1024) { o = bid & 7; bp = bid >> 3; }        // XCD k gets o=k
  else { const int ix = bid - 1024; o = 8 + (ix & 1); bp = ix >> 1; }
  const int b0 = bp * 2;
  __shared__ __attribute__((aligned(16))) float pri4[2][4608 * 4];  // 144KB
  __shared__ float red[2][8 * 17];
  __shared__ float redm[2][8];
  const int t = threadIdx.x;
  const int wave = t >> 6, lane = t & 63;
  const float* rwo = rwT + (size_t)o * 128 * 1152;
  const float* ub0 = u + (size_t)b0 * 9216;
  const float* ub1 = ub0 + 9216;
#pragma unroll
  for (int ci = 0; ci < 3; ci++) {
    const bool valid = (ci < 2) || (t < 128);
    const int i = valid ? (t + ci * 512) : 0;
    float uv0[8], uv1[8];
    *(float4*)&uv0[0] = *(const float4*)(ub0 + i * 8);
    *(float4*)&uv0[4] = *(const float4*)(ub0 + i * 8 + 4);
    *(float4*)&uv1[0] = *(const float4*)(ub1 + i * 8);
    *(float4*)&uv1[4] = *(const float4*)(ub1 + i * 8 + 4);
    float a0[16], a1[16];
#pragma unroll
    for (int d = 0; d < 16; d++) { a0[d] = 0.f; a1[d] = 0.f; }
#pragma unroll
    for (int c = 0; c < 8; c++) {
      const float* wcol = rwo + (size_t)(c * 16) * 1152 + i;  // lane-coalesced
#pragma unroll
      for (int d = 0; d < 16; d++) {
        const float wv = wcol[(size_t)d * 1152];
        a0[d] = fmaf(uv0[c], wv, a0[d]);
        a1[d] = fmaf(uv1[c], wv, a1[d]);
      }
    }
    if (valid) {
#pragma unroll
      for (int q = 0; q < 4; q++) {
        *(float4*)&pri4[0][(q * 1152 + i) * 4] = *(float4*)&a0[q * 4];
        *(float4*)&pri4[1][(q * 1152 + i) * 4] = *(float4*)&a1[q * 4];
      }
    }
  }
  __syncthreads();
  float l0[3], l1[3];
#pragma unroll
  for (int ci = 0; ci < 3; ci++) {
    const float init = ((ci < 2) || (t < 128)) ? 0.f : -1e30f;
    l0[ci] = init; l1[ci] = init;
  }
  float v0[16], v1[16];
#pragma unroll 1
  for (int it = 0; it < 3; it++) {
    float m0 = wmaxr(fmaxf(fmaxf(l0[0], l0[1]), l0[2]));
    float m1 = wmaxr(fmaxf(fmaxf(l1[0], l1[1]), l1[2]));
    if (lane == 0) { redm[0][wave] = m0; redm[1][wave] = m1; }
    __syncthreads();
    m0 = redm[0][0]; m1 = redm[1][0];
#pragma unroll
    for (int wv2 = 1; wv2 < 8; wv2++) {
      m0 = fmaxf(m0, redm[0][wv2]);
      m1 = fmaxf(m1, redm[1][wv2]);
    }
    float Z0 = 0.f, Z1 = 0.f, S0[16], S1[16];
#pragma unroll
    for (int d = 0; d < 16; d++) { S0[d] = 0.f; S1[d] = 0.f; }
#pragma unroll
    for (int ci = 0; ci < 3; ci++) {
      const bool valid = (ci < 2) || (t < 128);
      const int i = valid ? (t + ci * 512) : 0;
      const float e0 = expf(l0[ci] - m0);
      const float e1 = expf(l1[ci] - m1);
      Z0 += e0; Z1 += e1;
#pragma unroll
      for (int q = 0; q < 4; q++) {
        const float4 p0 = *(const float4*)&pri4[0][(q * 1152 + i) * 4];
        const float4 p1 = *(const float4*)&pri4[1][(q * 1152 + i) * 4];
        S0[q * 4 + 0] = fmaf(e0, p0.x, S0[q * 4 + 0]);
        S0[q * 4 + 1] = fmaf(e0, p0.y, S0[q * 4 + 1]);
        S0[q * 4 + 2] = fmaf(e0, p0.z, S0[q * 4 + 2]);
        S0[q * 4 + 3] = fmaf(e0, p0.w, S0[q * 4 + 3]);
        S1[q * 4 + 0] = fmaf(e1, p1.x, S1[q * 4 + 0]);
        S1[q * 4 + 1] = fmaf(e1, p1.y, S1[q * 4 + 1]);
        S1[q * 4 + 2] = fmaf(e1, p1.z, S1[q * 4 + 2]);
        S1[q * 4 + 3] = fmaf(e1, p1.w, S1[q * 4 + 3]);
      }
    }
    Z0 = wsum(Z0); Z1 = wsum(Z1);
#pragma unroll
    for (int d = 0; d < 16; d++) { S0[d] = wsum(S0[d]); S1[d] = wsum(S1[d]); }
    __syncthreads();                                 // red reuse fence
    if (lane == 0) {
      red[0][wave * 17] = Z0; red[1][wave * 17] = Z1;
#pragma unroll
      for (int d = 0; d < 16; d++) {
        red[0][wave * 17 + 1 + d] = S0[d];
        red[1][wave * 17 + 1 + d] = S1[d];
      }
    }
    __syncthreads();
    float Zt0 = 0.f, Zt1 = 0.f;
#pragma unroll
    for (int wv2 = 0; wv2 < 8; wv2++) { Zt0 += red[0][wv2 * 17]; Zt1 += red[1][wv2 * 17]; }
    float sq0 = 0.f, sq1 = 0.f;
#pragma unroll
    for (int d = 0; d < 16; d++) {
      float sd0 = 0.f, sd1 = 0.f;
#pragma unroll
      for (int wv2 = 0; wv2 < 8; wv2++) {
        sd0 += red[0][wv2 * 17 + 1 + d];
        sd1 += red[1][wv2 * 17 + 1 + d];
      }
      sd0 /= Zt0; sd1 /= Zt1;
      v0[d] = sd0; v1[d] = sd1;
      sq0 = fmaf(sd0, sd0, sq0);
      sq1 = fmaf(sd1, sd1, sq1);
    }
    const float sc0 = sq0 / ((1.f + sq0) * sqrtf(sq0));
    const float sc1 = sq1 / ((1.f + sq1) * sqrtf(sq1));
#pragma unroll
    for (int d = 0; d < 16; d++) { v0[d] *= sc0; v1[d] *= sc1; }
    if (it < 2) {
#pragma unroll
      for (int ci = 0; ci < 3; ci++) {
        const bool valid = (ci < 2) || (t < 128);
        const int i = valid ? (t + ci * 512) : 0;
        float d0 = 0.f, d1 = 0.f;
#pragma unroll
        for (int q = 0; q < 4; q++) {
          const float4 p0 = *(const float4*)&pri4[0][(q * 1152 + i) * 4];
          const float4 p1 = *(const float4*)&pri4[1][(q * 1152 + i) * 4];
          d0 = fmaf(p0.x, v0[q * 4 + 0], d0); d0 = fmaf(p0.y, v0[q * 4 + 1], d0);
          d0 = fmaf(p0.z, v0[q * 4 + 2], d0); d0 = fmaf(p0.w, v0[q * 4 + 3], d0);
          d1 = fmaf(p1.x, v1[q * 4 + 0], d1); d1 = fmaf(p1.y, v1[q * 4 + 1], d1);
          d1 = fmaf(p1.z, v1[q * 4 + 2], d1); d1 = fmaf(p1.w, v1[q * 4 + 3], d1);
        }
        l0[ci] += d0; l1[ci] += d1;
      }
    }
  }
  if (t == 0) {
    float* vb0 = vecs + ((size_t)b0 * 10 + o) * 16;
    float* vb1 = vecs + ((size_t)(b0 + 1) * 10 + o) * 16;
#pragma unroll
    for (int d = 0; d < 16; d++) { vb0[d] = v0[d]; vb1[d] = v1[d]; }
  }
}

// ====== dec1 (cls fused): classes softmax/argmax + first decoder layer =====
__global__ __launch_bounds__(512) void k_dec1(const float* __restrict__ vecs,
                                              const float* __restrict__ w1,
                                              const float* __restrict__ b1,
                                              float* __restrict__ out,
                                              float* __restrict__ h1) {
  const int b = blockIdx.x, t = threadIdx.x;
  __shared__ float vbs[160];
  __shared__ float sv[16];
  __shared__ int ams;
  const float* vb = vecs + (size_t)b * 160;
  if (t < 160) vbs[t] = vb[t];                      // coalesced
  __syncthreads();
  if (t == 0) {
    float nrm[10];
#pragma unroll
    for (int o = 0; o < 10; o++) {
      float sq = 0.f;
#pragma unroll
      for (int d = 0; d < 16; d++) { const float xv = vbs[o * 16 + d]; sq = fmaf(xv, xv, sq); }
      nrm[o] = sqrtf(sq);
    }
    float m = nrm[0];
#pragma unroll
    for (int o = 1; o < 10; o++) m = fmaxf(m, nrm[o]);
    float e[10], Z = 0.f;
#pragma unroll
    for (int o = 0; o < 10; o++) { e[o] = expf(nrm[o] - m); Z += e[o]; }
    const float inv = 1.f / Z;
    int am = 0;
    float best = e[0] * inv;
#pragma unroll
    for (int o = 0; o < 10; o++) {
      const float c = e[o] * inv;
      out[(size_t)b * 10 + o] = c;
      if (o > 0 && c > best) { best = c; am = o; }  // strict >: first-max
    }
    ams = am;
  }
  __syncthreads();
  const int am2 = ams;
  if (t < 16) sv[t] = vbs[am2 * 16 + t];
  __syncthreads();
  const float* wrow = w1 + (size_t)am2 * 16 * 512;
  float acc = b1[t];
#pragma unroll
  for (int d = 0; d < 16; d++) acc = fmaf(sv[d], wrow[d * 512 + t], acc);
  h1[(size_t)b * 512 + t] = fmaxf(acc, 0.f);
}

// dec2 v2: 2 imgs x 128 n per block (grid 1024); w2 in 32-k LDS tiles.
__global__ __launch_bounds__(128) void k_dec2(const float* __restrict__ h1,
                                              const float* __restrict__ w2,
                                              const float* __restrict__ b2,
                                              float* __restrict__ h2) {
  const int nc = blockIdx.x >> 7, bg = blockIdx.x & 127;
  const int t = threadIdx.x;
  const int n = nc * 128 + t;
  const int bs = bg * 2;
  __shared__ float h1s[2 * 512];
  __shared__ float wts[32 * 128];
  {
    const float4* src = (const float4*)(h1 + (size_t)bs * 512);
    for (int i = t; i < 256; i += 128) ((float4*)h1s)[i] = src[i];
  }
  float acc[2];
  const float bb = b2[n];
  acc[0] = bb; acc[1] = bb;
#pragma unroll 1
  for (int kt = 0; kt < 16; kt++) {
    __syncthreads();
#pragma unroll
    for (int r = 0; r < 32; r++)
      wts[r * 128 + t] = w2[(size_t)(kt * 32 + r) * 1024 + n];
    __syncthreads();
#pragma unroll
    for (int k4 = 0; k4 < 8; k4++) {
      float wq[4];
#pragma unroll
      for (int q = 0; q < 4; q++) wq[q] = wts[(k4 * 4 + q) * 128 + t];
#pragma unroll
      for (int j = 0; j < 2; j++) {
        const float4 hv = *(const float4*)&h1s[j * 512 + kt * 32 + k4 * 4];
        acc[j] = fmaf(hv.x, wq[0], acc[j]);
        acc[j] = fmaf(hv.y, wq[1], acc[j]);
        acc[j] = fmaf(hv.z, wq[2], acc[j]);
        acc[j] = fmaf(hv.w, wq[3], acc[j]);
      }
    }
  }
#pragma unroll
  for (int j = 0; j < 2; j++) h2[(size_t)(bs + j) * 1024 + n] = fmaxf(acc[j], 0.f);
}

// dec3 v2: 2 imgs x 112 n per block (grid 896); w3 in 32-k LDS tiles.
__global__ __launch_bounds__(128) void k_dec3(const float* __restrict__ h2,
                                              const float* __restrict__ w3,
                                              const float* __restrict__ b3,
                                              float* __restrict__ out) {
  const int nc = blockIdx.x >> 7, bg = blockIdx.x & 127;
  const int t = threadIdx.x;
  const int bs = bg * 2;
  __shared__ float h2s[2 * 1024];
  __shared__ float wts[32 * 112];
  {
    const float4* src = (const float4*)(h2 + (size_t)bs * 1024);
    for (int i = t; i < 512; i += 128) ((float4*)h2s)[i] = src[i];
  }
  const int n = nc * 112 + (t < 112 ? t : 0);
  float acc[2];
  const float bb = b3[n];
  acc[0] = bb; acc[1] = bb;
#pragma unroll 1
  for (int kt = 0; kt < 32; kt++) {
    __syncthreads();
#pragma unroll
    for (int r = 0; r < 32; r++)
      if (t < 112) wts[r * 112 + t] = w3[(size_t)(kt * 32 + r) * 784 + n];
    __syncthreads();
    if (t < 112) {
#pragma unroll
      for (int k4 = 0; k4 < 8; k4++) {
        float wq[4];
#pragma unroll
        for (int q = 0; q < 4; q++) wq[q] = wts[(k4 * 4 + q) * 112 + t];
#pragma unroll
        for (int j = 0; j < 2; j++) {
          const float4 hv = *(const float4*)&h2s[j * 1024 + kt * 32 + k4 * 4];
          acc[j] = fmaf(hv.x, wq[0], acc[j]);
          acc[j] = fmaf(hv.y, wq[1], acc[j]);
          acc[j] = fmaf(hv.z, wq[2], acc[j]);
          acc[j] = fmaf(hv.w, wq[3], acc[j]);
        }
      }
    }
  }
  if (t < 112) {
#pragma unroll
    for (int j = 0; j < 2; j++)
      out[(size_t)(bs + j) * 784 + n] = 1.f / (1.f + expf(-acc[j]));
  }
}

// ============================= launcher ====================================
extern "C" void kernel_launch(void* const* d_in, const int* in_sizes, int n_in,
                              void* d_out, int out_size, void* d_ws, size_t ws_size,
                              hipStream_t stream) {
  const float* x   = (const float*)d_in[0];
  const float* c1w = (const float*)d_in[1];
  const float* c1b = (const float*)d_in[2];
  const float* pw  = (const float*)d_in[3];
  const float* pb  = (const float*)d_in[4];
  const float* rw  = (const float*)d_in[5];
  const float* w1  = (const float*)d_in[6];
  const float* b1  = (const float*)d_in[7];
  const float* w2  = (const float*)d_in[8];
  const float* b2  = (const float*)d_in[9];
  const float* w3  = (const float*)d_in[10];
  const float* b3  = (const float*)d_in[11];
  float* out = (float*)d_out;
  float* ws = (float*)d_ws;

  // wGp padded by one extra step (18432 B) for the K-loop W prefetch overrun
  const size_t WGP_F = ((size_t)672 * 4 * 4608 + 18432) / 4;
  const size_t U_F = 2359296;
  const size_t RWT_F = 10 * 128 * 1152;                // 1.47M floats
  const size_t SMALL_F = 40960 + 4096 + 256 + 131072 + 262144;
  const size_t fixed_f = WGP_F + 2 * PQ_F + U_F + RWT_F + SMALL_F;
  // hTgc floats per img: 32ch * 820 chunks * 16B / 4 = 104960
  int chunk = 256;
  while (chunk > 8 && (fixed_f + (size_t)chunk * 104960) * 4 > ws_size) chunk >>= 1;

  __hip_bfloat16* wGp  = (__hip_bfloat16*)ws;
  __hip_bfloat16* hTgc = (__hip_bfloat16*)(ws + WGP_F);
  float* pq   = ws + WGP_F + (size_t)chunk * 104960;   // 2 partial buffers
  float* u    = pq + 2 * PQ_F;
  float* rwT  = u + U_F;
  float* vecs = rwT + RWT_F;
  float* h1   = vecs + 40960 + 4096 + 256;
  float* h2   = h1 + 131072;

  if (chunk == 256) {
    k_prep<<<dim3(3892), dim3(256), 0, stream>>>(pw, wGp, rw, rwT, x, c1w, c1b, hTgc);
    k_conv2<<<dim3(512), dim3(512), 0, stream>>>(hTgc, wGp, pq, 0);
  } else {
    k_prep<<<dim3(2868), dim3(256), 0, stream>>>(pw, wGp, rw, rwT, x, c1w, c1b, hTgc);
    for (int c0 = 0; c0 < 256; c0 += chunk) {
      k_prep<<<dim3(chunk * 4), dim3(256), 0, stream>>>(   // conv1-only range
          pw, wGp, rw, rwT, x + (size_t)c0 * 784, c1w, c1b, hTgc);
      // note: conv1-only path reuses k_prep's conv1 branch via bid offset —
      // fallback not exercised when ws is large enough (chunk==256).
      k_conv2<<<dim3((chunk / 4) * 8), dim3(512), 0, stream>>>(hTgc, wGp, pq, c0);
    }
  }
  k_squash<<<dim3(256), dim3(256), 0, stream>>>(pq, pb, u);
  k_route<<<dim3(1280), dim3(512), 0, stream>>>(u, rwT, vecs);
  k_dec1<<<dim3(256), dim3(512), 0, stream>>>(vecs, w1, b1, out, h1);
  k_dec2<<<dim3(1024), dim3(128), 0, stream>>>(h1, w2, b2, h2);
  k_dec3<<<dim3(896), dim3(128), 0, stream>>>(h2, w3, b3, out + 2560);
}

// Round 15
// 749.446 us; speedup vs baseline: 1.0787x; 1.0787x over previous
//
#include <hip/hip_runtime.h>
#include <hip/hip_bf16.h>
#include <math.h>

// ---------------------------------------------------------------------------
// CapsNet forward. R15 = measured-best recombine:
//  - conv2 = R13 version (uniform mhalf blocking, 259us, MfmaUtil 58%).
//    R14's M-group split halved conflicts (5.6e7->2.8e7) but unbalanced
//    waves (18 vs 12 MFMA/step) -> +27% critical path. Conflicts are
//    overlapped, balance wins.
//  - k_prep merge from R14 (wrep+rrep+conv1 one dispatch, measured ~-31us).
//  - route v5 / squash v2 / dec* v2 unchanged.
// ---------------------------------------------------------------------------

typedef __attribute__((ext_vector_type(8))) short bf16x8;
typedef __attribute__((ext_vector_type(4))) float f32x4;

__device__ __forceinline__ void gl16(const void* g, void* l) {
  __builtin_amdgcn_global_load_lds((const __attribute__((address_space(1))) void*)g,
                                   (__attribute__((address_space(3))) void*)l,
                                   16, 0, 0);
}

// ==== k_prep: [0,2688) wrep | [2688,2868) rrep | [2868,3892) conv1 =========
__global__ __launch_bounds__(256) void k_prep(
    const float* __restrict__ pw, __hip_bfloat16* __restrict__ wGp,
    const float* __restrict__ rw, float* __restrict__ rwT,
    const float* __restrict__ x, const float* __restrict__ c1w,
    const float* __restrict__ c1b, __hip_bfloat16* __restrict__ hT) {
  __shared__ __attribute__((aligned(16))) char smem[44480];
  const int bid = blockIdx.x;
  const int t = threadIdx.x;
  if (bid < 2688) {                                 // ---- wrep ----
    const int s = bid >> 2, ocq = bid & 3;          // s in [0,672)
    const int ch = s / 21, tq = s - ch * 21;
    __hip_bfloat16* outp = wGp + ((size_t)s * 4 + ocq) * 4608;
    for (int e = t; e < 2048; e += 256) {
      const int ocl = e >> 5, k = e & 31;
      const int tapl = k >> 3, icl = k & 7;
      const int tap = tq * 4 + tapl, ic = ch * 8 + icl;
      const int oc = ocq * 64 + ocl;
      const float v = (tap < 81) ? pw[((size_t)oc * 256 + ic) * 81 + tap] : 0.f;
      const __hip_bfloat16 hi = __float2bfloat16(v);
      const __hip_bfloat16 lo = __float2bfloat16(v - __bfloat162float(hi));
      outp[ocl * 72 + k] = hi;
      outp[ocl * 72 + 32 + k] = lo;
    }
    for (int e = t; e < 512; e += 256) {
      const int ocl = e >> 3, j = e & 7;
      outp[ocl * 72 + 64 + j] = __float2bfloat16(0.f);
    }
  } else if (bid < 2868) {                          // ---- rrep ----
    float* tile = (float*)smem;                     // 64*129 floats (33KB)
    const int bb = bid - 2688;
    const int o = bb / 18, ig = bb % 18;
    for (int idx = t; idx < 64 * 128; idx += 256) {
      const int i = idx >> 7, cd = idx & 127;
      tile[i * 129 + cd] = rw[((size_t)o * 1152 + ig * 64 + i) * 128 + cd];
    }
    __syncthreads();
    for (int idx = t; idx < 64 * 128; idx += 256) {
      const int cd = idx >> 6, il = idx & 63;
      rwT[((size_t)o * 128 + cd) * 1152 + ig * 64 + il] = tile[il * 129 + cd];
    }
  } else {                                          // ---- conv1 ----
    const int bb = bid - 2868;
    const int img = bb >> 2, ocq = bb & 3;          // 64 oc per block
    float* xs = (float*)smem;                       // 784 f
    float* ws = xs + 784;                           // 5184 f
    __hip_bfloat16* tile = (__hip_bfloat16*)(ws + 5184);  // 8*1288 bf16
    const float4* xg = (const float4*)(x + (size_t)img * 784);
    if (t < 196) ((float4*)xs)[t] = xg[t];
    const float4* wg = (const float4*)(c1w + (size_t)ocq * 64 * 81);
    for (int i = t; i < 1296; i += 256) ((float4*)ws)[i] = wg[i];
    __syncthreads();
    const int ocl = t & 63, rowg = t >> 6;          // wave = rowg
    const int oc = ocq * 64 + ocl;
    const int chl = ocl >> 3, icl = ocl & 7;
    const float bv = c1b[oc];
    __hip_bfloat16* hb = hT + ((size_t)img * 32 + ocq * 8) * 6560;
#pragma unroll 1
    for (int it = 0; it < 5; it++) {
      const int r = it * 4 + rowg;                  // y
      float acc[20];
#pragma unroll
      for (int p = 0; p < 20; p++) acc[p] = bv;
#pragma unroll
      for (int ky = 0; ky < 9; ky++) {
        float xr[28];
        const float* xrow = &xs[(r + ky) * 28];
#pragma unroll
        for (int q = 0; q < 7; q++) ((float4*)xr)[q] = ((const float4*)xrow)[q];
        float wr[9];
#pragma unroll
        for (int i = 0; i < 9; i++) wr[i] = ws[ocl * 81 + ky * 9 + i];
#pragma unroll
        for (int kx = 0; kx < 9; kx++)
#pragma unroll
          for (int p = 0; p < 20; p++)
            acc[p] = fmaf(wr[kx], xr[p + kx], acc[p]);
      }
#pragma unroll
      for (int p = 0; p < 20; p++) {                // p = x
        const float v = fmaxf(acc[p], 0.f);
        const __hip_bfloat16 hi = __float2bfloat16(v);
        const __hip_bfloat16 lo = __float2bfloat16(v - __bfloat162float(hi));
        tile[chl * 1288 + (p * 8 + rowg * 2) * 8 + icl] = hi;
        tile[chl * 1288 + (p * 8 + rowg * 2 + 1) * 8 + icl] = lo;
      }
      __syncthreads();
#pragma unroll
      for (int q = 0; q < 5; q++) {                 // 1280 16B chunks
        const int idx = q * 256 + t;
        const int c2 = idx / 160, rem = idx - c2 * 160;
        const int xx = rem >> 3, j = rem & 7;
        const float4 vdat = *(const float4*)&tile[c2 * 1288 + rem * 8];
        *(float4*)(hb + (size_t)c2 * 6560 + (size_t)(xx * 41 + it * 8 + j) * 8) = vdat;
      }
      __syncthreads();
    }
  }
}

// ====== conv2 MFMA (R13): pq[kq][img][px36][oc256] partial over 16 ch ======
#define HT_B 52480              // 3280 chunks x 16B  (4 img x 820)
#define PQ_F 2359296
__global__ __launch_bounds__(512) void k_conv2(
    const __hip_bfloat16* __restrict__ hTg,    // [chunk img][32ch][820ch][8]
    const __hip_bfloat16* __restrict__ wGp,    // [672][4ocq][4608B] (+1 pad step)
    float* __restrict__ pq, int c0) {
  __shared__ char hT[HT_B];
  const int bid = blockIdx.x;
  int ig, ocq, kq;
  if (gridDim.x == 512) {       // XCD swizzle: ocq sharers keep bid%8
    ig = (bid & 7) | (((bid >> 5) & 7) << 3);
    ocq = (bid >> 3) & 3;
    kq = bid >> 8;
  } else {
    ig = bid >> 3;
    ocq = (bid >> 1) & 3;
    kq = bid & 1;
  }
  const int t = threadIdx.x;
  const int w = t >> 6, lane = t & 63;
  const int lquad = lane >> 4, lrow = lane & 15;
  const int mhalf = w >> 2;
  const int nt = mhalf ? 4 : 5;
  const int mtb = mhalf ? 5 : 0;
  const int ocg = ocq * 64 + (w & 3) * 16 + lrow;
  int abase[5];
#pragma unroll
  for (int i = 0; i < 5; i++) {
    int m = (mtb + i) * 16 + lrow;
    if (i >= nt) m = 0;
    const int img = m / 36, px = m - img * 36;
    const int oy = px / 6, ox = px - oy * 6;
    abase[i] = img * 13120 + ox * 1312 + oy * 64;   // bytes in hT
  }
  f32x4 acc[5];
#pragma unroll
  for (int i = 0; i < 5; i++) acc[i] = (f32x4){0.f, 0.f, 0.f, 0.f};

  const char* hgc = (const char*)hTg;
  const char* wp = (const char*)wGp + ((size_t)(kq * 336) * 4 + ocq) * 4608 +
                   ((w & 3) * 16 + lrow) * 144 + lquad * 16;
  bf16x8 bh = *(const bf16x8*)wp;
  bf16x8 bl = *(const bf16x8*)(wp + 64);
  wp += 18432;
#pragma unroll 1
  for (int chl = 0; chl < 16; chl++) {
    const int ch = kq * 16 + chl;
    const char* hch = hgc + ((size_t)(ig * 128) + ch) * 13120;
#pragma unroll
    for (int rr = 0; rr < 6; rr++) {
      const int idx = t + rr * 512;
      const int j = idx / 820, r = idx - j * 820;
      gl16(hch + (size_t)j * 419840 + r * 16, hT + rr * 8192 + w * 1024);
    }
    if (t < 208) {
      const int idx = 3072 + t;
      const int j = idx / 820, r = idx - j * 820;
      gl16(hch + (size_t)j * 419840 + r * 16, hT + 49152 + w * 1024);
    }
    __syncthreads();
#pragma unroll 1
    for (int tq = 0; tq < 21; tq++) {
      const bf16x8 nh = *(const bf16x8*)wp;         // prefetch next step's W
      const bf16x8 nl = *(const bf16x8*)(wp + 64);
      wp += 18432;
      const int tt = tq * 4 + lquad;                // this quad's tap
      const int ky = tt / 9, kx = tt - ky * 9;
      const int toff = kx * 656 + ky * 32;          // (kx*41 + ky*2) chunks
      bf16x8 ah[5];
#pragma unroll
      for (int i = 0; i < 5; i++)
        ah[i] = *(const bf16x8*)(hT + abase[i] + toff);
#pragma unroll
      for (int i = 0; i < 5; i++)
        if (i < nt) acc[i] = __builtin_amdgcn_mfma_f32_16x16x32_bf16(ah[i], bh, acc[i], 0, 0, 0);
#pragma unroll
      for (int i = 0; i < 5; i++)
        if (i < nt) acc[i] = __builtin_amdgcn_mfma_f32_16x16x32_bf16(ah[i], bl, acc[i], 0, 0, 0);
      bf16x8 al[5];
#pragma unroll
      for (int i = 0; i < 5; i++)
        al[i] = *(const bf16x8*)(hT + abase[i] + toff + 16);
#pragma unroll
      for (int i = 0; i < 5; i++)
        if (i < nt) acc[i] = __builtin_amdgcn_mfma_f32_16x16x32_bf16(al[i], bh, acc[i], 0, 0, 0);
      bh = nh;
      bl = nl;
    }
    __syncthreads();                                // hT reuse fence
  }
  float* pblk = pq + (size_t)kq * PQ_F;
#pragma unroll
  for (int i = 0; i < 5; i++) {
    if (i < nt) {
#pragma unroll
      for (int r = 0; r < 4; r++) {
        const int m = (mtb + i) * 16 + lquad * 4 + r;   // D row = quad*4+reg
        const int img = m / 36, px = m - img * 36;
        pblk[((size_t)(c0 + ig * 4 + img) * 36 + px) * 256 + ocg] = acc[i][r];
      }
    }
  }
}

// ===== squash v2: block/b, LDS-staged coalesced ============================
__global__ __launch_bounds__(256) void k_squash(const float* __restrict__ pq,
                                                const float* __restrict__ bias,
                                                float* __restrict__ u) {
  const int b = blockIdx.x;
  __shared__ float ps[36 * 257];
  const int t = threadIdx.x;
  const float4* s0 = (const float4*)(pq + (size_t)b * 9216);
  const float4* s1 = (const float4*)(pq + (size_t)PQ_F + (size_t)b * 9216);
#pragma unroll
  for (int q = 0; q < 9; q++) {                     // 2304 float4, coalesced
    const int idx = q * 256 + t;
    const float4 a = s0[idx], c = s1[idx];
    const int px = idx >> 6, oc = (idx & 63) * 4;
    float* dst = &ps[px * 257 + oc];
    dst[0] = a.x + c.x; dst[1] = a.y + c.y;
    dst[2] = a.z + c.z; dst[3] = a.w + c.w;
  }
  __syncthreads();
#pragma unroll
  for (int rr = 0; rr < 5; rr++) {
    const int i = rr * 256 + t;
    if (i < 1152) {
      const int cp = i / 36, px = i - cp * 36;
      float s[8], sq = 0.f;
#pragma unroll
      for (int d = 0; d < 8; d++) {
        s[d] = ps[px * 257 + d * 32 + cp] + bias[d * 32 + cp];
        sq = fmaf(s[d], s[d], sq);
      }
      const float scale = sq / ((1.f + sq) * sqrtf(sq));
      float o[8];
#pragma unroll
      for (int d = 0; d < 8; d++) o[d] = s[d] * scale;
      float* ub = u + ((size_t)b * 1152 + i) * 8;
      ((float4*)ub)[0] = ((float4*)o)[0];
      ((float4*)ub)[1] = ((float4*)o)[1];
    }
  }
}

// ======================= routing by agreement ==============================
__device__ __forceinline__ float wsum(float v) {
#pragma unroll
  for (int o = 32; o > 0; o >>= 1) v += __shfl_xor(v, o, 64);
  return v;
}
__device__ __forceinline__ float wmaxr(float v) {
#pragma unroll
  for (int o = 32; o > 0; o >>= 1) v = fmaxf(v, __shfl_xor(v, o, 64));
  return v;
}

// route v5: 2 imgs per block, priors fp32 in LDS (144KB), rwT read once.
__global__ __launch_bounds__(512) void k_route(const float* __restrict__ u,
                                               const float* __restrict__ rwT,
                                               float* __restrict__ vecs) {
  const int bid = blockIdx.x;
  int o, bp;
  if (bid < 1024) { o = bid & 7; bp = bid >> 3; }        // XCD k gets o=k
  else { const int ix = bid - 1024; o = 8 + (ix & 1); bp = ix >> 1; }
  const int b0 = bp * 2;
  __shared__ __attribute__((aligned(16))) float pri4[2][4608 * 4];  // 144KB
  __shared__ float red[2][8 * 17];
  __shared__ float redm[2][8];
  const int t = threadIdx.x;
  const int wave = t >> 6, lane = t & 63;
  const float* rwo = rwT + (size_t)o * 128 * 1152;
  const float* ub0 = u + (size_t)b0 * 9216;
  const float* ub1 = ub0 + 9216;
#pragma unroll
  for (int ci = 0; ci < 3; ci++) {
    const bool valid = (ci < 2) || (t < 128);
    const int i = valid ? (t + ci * 512) : 0;
    float uv0[8], uv1[8];
    *(float4*)&uv0[0] = *(const float4*)(ub0 + i * 8);
    *(float4*)&uv0[4] = *(const float4*)(ub0 + i * 8 + 4);
    *(float4*)&uv1[0] = *(const float4*)(ub1 + i * 8);
    *(float4*)&uv1[4] = *(const float4*)(ub1 + i * 8 + 4);
    float a0[16], a1[16];
#pragma unroll
    for (int d = 0; d < 16; d++) { a0[d] = 0.f; a1[d] = 0.f; }
#pragma unroll
    for (int c = 0; c < 8; c++) {
      const float* wcol = rwo + (size_t)(c * 16) * 1152 + i;  // lane-coalesced
#pragma unroll
      for (int d = 0; d < 16; d++) {
        const float wv = wcol[(size_t)d * 1152];
        a0[d] = fmaf(uv0[c], wv, a0[d]);
        a1[d] = fmaf(uv1[c], wv, a1[d]);
      }
    }
    if (valid) {
#pragma unroll
      for (int q = 0; q < 4; q++) {
        *(float4*)&pri4[0][(q * 1152 + i) * 4] = *(float4*)&a0[q * 4];
        *(float4*)&pri4[1][(q * 1152 + i) * 4] = *(float4*)&a1[q * 4];
      }
    }
  }
  __syncthreads();
  float l0[3], l1[3];
#pragma unroll
  for (int ci = 0; ci < 3; ci++) {
    const float init = ((ci < 2) || (t < 128)) ? 0.f : -1e30f;
    l0[ci] = init; l1[ci] = init;
  }
  float v0[16], v1[16];
#pragma unroll 1
  for (int it = 0; it < 3; it++) {
    float m0 = wmaxr(fmaxf(fmaxf(l0[0], l0[1]), l0[2]));
    float m1 = wmaxr(fmaxf(fmaxf(l1[0], l1[1]), l1[2]));
    if (lane == 0) { redm[0][wave] = m0; redm[1][wave] = m1; }
    __syncthreads();
    m0 = redm[0][0]; m1 = redm[1][0];
#pragma unroll
    for (int wv2 = 1; wv2 < 8; wv2++) {
      m0 = fmaxf(m0, redm[0][wv2]);
      m1 = fmaxf(m1, redm[1][wv2]);
    }
    float Z0 = 0.f, Z1 = 0.f, S0[16], S1[16];
#pragma unroll
    for (int d = 0; d < 16; d++) { S0[d] = 0.f; S1[d] = 0.f; }
#pragma unroll
    for (int ci = 0; ci < 3; ci++) {
      const bool valid = (ci < 2) || (t < 128);
      const int i = valid ? (t + ci * 512) : 0;
      const float e0 = expf(l0[ci] - m0);
      const float e1 = expf(l1[ci] - m1);
      Z0 += e0; Z1 += e1;
#pragma unroll
      for (int q = 0; q < 4; q++) {
        const float4 p0 = *(const float4*)&pri4[0][(q * 1152 + i) * 4];
        const float4 p1 = *(const float4*)&pri4[1][(q * 1152 + i) * 4];
        S0[q * 4 + 0] = fmaf(e0, p0.x, S0[q * 4 + 0]);
        S0[q * 4 + 1] = fmaf(e0, p0.y, S0[q * 4 + 1]);
        S0[q * 4 + 2] = fmaf(e0, p0.z, S0[q * 4 + 2]);
        S0[q * 4 + 3] = fmaf(e0, p0.w, S0[q * 4 + 3]);
        S1[q * 4 + 0] = fmaf(e1, p1.x, S1[q * 4 + 0]);
        S1[q * 4 + 1] = fmaf(e1, p1.y, S1[q * 4 + 1]);
        S1[q * 4 + 2] = fmaf(e1, p1.z, S1[q * 4 + 2]);
        S1[q * 4 + 3] = fmaf(e1, p1.w, S1[q * 4 + 3]);
      }
    }
    Z0 = wsum(Z0); Z1 = wsum(Z1);
#pragma unroll
    for (int d = 0; d < 16; d++) { S0[d] = wsum(S0[d]); S1[d] = wsum(S1[d]); }
    __syncthreads();                                 // red reuse fence
    if (lane == 0) {
      red[0][wave * 17] = Z0; red[1][wave * 17] = Z1;
#pragma unroll
      for (int d = 0; d < 16; d++) {
        red[0][wave * 17 + 1 + d] = S0[d];
        red[1][wave * 17 + 1 + d] = S1[d];
      }
    }
    __syncthreads();
    float Zt0 = 0.f, Zt1 = 0.f;
#pragma unroll
    for (int wv2 = 0; wv2 < 8; wv2++) { Zt0 += red[0][wv2 * 17]; Zt1 += red[1][wv2 * 17]; }
    float sq0 = 0.f, sq1 = 0.f;
#pragma unroll
    for (int d = 0; d < 16; d++) {
      float sd0 = 0.f, sd1 = 0.f;
#pragma unroll
      for (int wv2 = 0; wv2 < 8; wv2++) {
        sd0 += red[0][wv2 * 17 + 1 + d];
        sd1 += red[1][wv2 * 17 + 1 + d];
      }
      sd0 /= Zt0; sd1 /= Zt1;
      v0[d] = sd0; v1[d] = sd1;
      sq0 = fmaf(sd0, sd0, sq0);
      sq1 = fmaf(sd1, sd1, sq1);
    }
    const float sc0 = sq0 / ((1.f + sq0) * sqrtf(sq0));
    const float sc1 = sq1 / ((1.f + sq1) * sqrtf(sq1));
#pragma unroll
    for (int d = 0; d < 16; d++) { v0[d] *= sc0; v1[d] *= sc1; }
    if (it < 2) {
#pragma unroll
      for (int ci = 0; ci < 3; ci++) {
        const bool valid = (ci < 2) || (t < 128);
        const int i = valid ? (t + ci * 512) : 0;
        float d0 = 0.f, d1 = 0.f;
#pragma unroll
        for (int q = 0; q < 4; q++) {
          const float4 p0 = *(const float4*)&pri4[0][(q * 1152 + i) * 4];
          const float4 p1 = *(const float4*)&pri4[1][(q * 1152 + i) * 4];
          d0 = fmaf(p0.x, v0[q * 4 + 0], d0); d0 = fmaf(p0.y, v0[q * 4 + 1], d0);
          d0 = fmaf(p0.z, v0[q * 4 + 2], d0); d0 = fmaf(p0.w, v0[q * 4 + 3], d0);
          d1 = fmaf(p1.x, v1[q * 4 + 0], d1); d1 = fmaf(p1.y, v1[q * 4 + 1], d1);
          d1 = fmaf(p1.z, v1[q * 4 + 2], d1); d1 = fmaf(p1.w, v1[q * 4 + 3], d1);
        }
        l0[ci] += d0; l1[ci] += d1;
      }
    }
  }
  if (t == 0) {
    float* vb0 = vecs + ((size_t)b0 * 10 + o) * 16;
    float* vb1 = vecs + ((size_t)(b0 + 1) * 10 + o) * 16;
#pragma unroll
    for (int d = 0; d < 16; d++) { vb0[d] = v0[d]; vb1[d] = v1[d]; }
  }
}

// ====== dec1 (cls fused): classes softmax/argmax + first decoder layer =====
__global__ __launch_bounds__(512) void k_dec1(const float* __restrict__ vecs,
                                              const float* __restrict__ w1,
                                              const float* __restrict__ b1,
                                              float* __restrict__ out,
                                              float* __restrict__ h1) {
  const int b = blockIdx.x, t = threadIdx.x;
  __shared__ float vbs[160];
  __shared__ float sv[16];
  __shared__ int ams;
  const float* vb = vecs + (size_t)b * 160;
  if (t < 160) vbs[t] = vb[t];                      // coalesced
  __syncthreads();
  if (t == 0) {
    float nrm[10];
#pragma unroll
    for (int o = 0; o < 10; o++) {
      float sq = 0.f;
#pragma unroll
      for (int d = 0; d < 16; d++) { const float xv = vbs[o * 16 + d]; sq = fmaf(xv, xv, sq); }
      nrm[o] = sqrtf(sq);
    }
    float m = nrm[0];
#pragma unroll
    for (int o = 1; o < 10; o++) m = fmaxf(m, nrm[o]);
    float e[10], Z = 0.f;
#pragma unroll
    for (int o = 0; o < 10; o++) { e[o] = expf(nrm[o] - m); Z += e[o]; }
    const float inv = 1.f / Z;
    int am = 0;
    float best = e[0] * inv;
#pragma unroll
    for (int o = 0; o < 10; o++) {
      const float c = e[o] * inv;
      out[(size_t)b * 10 + o] = c;
      if (o > 0 && c > best) { best = c; am = o; }  // strict >: first-max
    }
    ams = am;
  }
  __syncthreads();
  const int am2 = ams;
  if (t < 16) sv[t] = vbs[am2 * 16 + t];
  __syncthreads();
  const float* wrow = w1 + (size_t)am2 * 16 * 512;
  float acc = b1[t];
#pragma unroll
  for (int d = 0; d < 16; d++) acc = fmaf(sv[d], wrow[d * 512 + t], acc);
  h1[(size_t)b * 512 + t] = fmaxf(acc, 0.f);
}

// dec2 v2: 2 imgs x 128 n per block (grid 1024); w2 in 32-k LDS tiles.
__global__ __launch_bounds__(128) void k_dec2(const float* __restrict__ h1,
                                              const float* __restrict__ w2,
                                              const float* __restrict__ b2,
                                              float* __restrict__ h2) {
  const int nc = blockIdx.x >> 7, bg = blockIdx.x & 127;
  const int t = threadIdx.x;
  const int n = nc * 128 + t;
  const int bs = bg * 2;
  __shared__ float h1s[2 * 512];
  __shared__ float wts[32 * 128];
  {
    const float4* src = (const float4*)(h1 + (size_t)bs * 512);
    for (int i = t; i < 256; i += 128) ((float4*)h1s)[i] = src[i];
  }
  float acc[2];
  const float bb = b2[n];
  acc[0] = bb; acc[1] = bb;
#pragma unroll 1
  for (int kt = 0; kt < 16; kt++) {
    __syncthreads();
#pragma unroll
    for (int r = 0; r < 32; r++)
      wts[r * 128 + t] = w2[(size_t)(kt * 32 + r) * 1024 + n];
    __syncthreads();
#pragma unroll
    for (int k4 = 0; k4 < 8; k4++) {
      float wq[4];
#pragma unroll
      for (int q = 0; q < 4; q++) wq[q] = wts[(k4 * 4 + q) * 128 + t];
#pragma unroll
      for (int j = 0; j < 2; j++) {
        const float4 hv = *(const float4*)&h1s[j * 512 + kt * 32 + k4 * 4];
        acc[j] = fmaf(hv.x, wq[0], acc[j]);
        acc[j] = fmaf(hv.y, wq[1], acc[j]);
        acc[j] = fmaf(hv.z, wq[2], acc[j]);
        acc[j] = fmaf(hv.w, wq[3], acc[j]);
      }
    }
  }
#pragma unroll
  for (int j = 0; j < 2; j++) h2[(size_t)(bs + j) * 1024 + n] = fmaxf(acc[j], 0.f);
}

// dec3 v2: 2 imgs x 112 n per block (grid 896); w3 in 32-k LDS tiles.
__global__ __launch_bounds__(128) void k_dec3(const float* __restrict__ h2,
                                              const float* __restrict__ w3,
                                              const float* __restrict__ b3,
                                              float* __restrict__ out) {
  const int nc = blockIdx.x >> 7, bg = blockIdx.x & 127;
  const int t = threadIdx.x;
  const int bs = bg * 2;
  __shared__ float h2s[2 * 1024];
  __shared__ float wts[32 * 112];
  {
    const float4* src = (const float4*)(h2 + (size_t)bs * 1024);
    for (int i = t; i < 512; i += 128) ((float4*)h2s)[i] = src[i];
  }
  const int n = nc * 112 + (t < 112 ? t : 0);
  float acc[2];
  const float bb = b3[n];
  acc[0] = bb; acc[1] = bb;
#pragma unroll 1
  for (int kt = 0; kt < 32; kt++) {
    __syncthreads();
#pragma unroll
    for (int r = 0; r < 32; r++)
      if (t < 112) wts[r * 112 + t] = w3[(size_t)(kt * 32 + r) * 784 + n];
    __syncthreads();
    if (t < 112) {
#pragma unroll
      for (int k4 = 0; k4 < 8; k4++) {
        float wq[4];
#pragma unroll
        for (int q = 0; q < 4; q++) wq[q] = wts[(k4 * 4 + q) * 112 + t];
#pragma unroll
        for (int j = 0; j < 2; j++) {
          const float4 hv = *(const float4*)&h2s[j * 1024 + kt * 32 + k4 * 4];
          acc[j] = fmaf(hv.x, wq[0], acc[j]);
          acc[j] = fmaf(hv.y, wq[1], acc[j]);
          acc[j] = fmaf(hv.z, wq[2], acc[j]);
          acc[j] = fmaf(hv.w, wq[3], acc[j]);
        }
      }
    }
  }
  if (t < 112) {
#pragma unroll
    for (int j = 0; j < 2; j++)
      out[(size_t)(bs + j) * 784 + n] = 1.f / (1.f + expf(-acc[j]));
  }
}

// ============================= launcher ====================================
extern "C" void kernel_launch(void* const* d_in, const int* in_sizes, int n_in,
                              void* d_out, int out_size, void* d_ws, size_t ws_size,
                              hipStream_t stream) {
  const float* x   = (const float*)d_in[0];
  const float* c1w = (const float*)d_in[1];
  const float* c1b = (const float*)d_in[2];
  const float* pw  = (const float*)d_in[3];
  const float* pb  = (const float*)d_in[4];
  const float* rw  = (const float*)d_in[5];
  const float* w1  = (const float*)d_in[6];
  const float* b1  = (const float*)d_in[7];
  const float* w2  = (const float*)d_in[8];
  const float* b2  = (const float*)d_in[9];
  const float* w3  = (const float*)d_in[10];
  const float* b3  = (const float*)d_in[11];
  float* out = (float*)d_out;
  float* ws = (float*)d_ws;

  const size_t WGP_F = ((size_t)672 * 4 * 4608 + 18432) / 4;
  const size_t U_F = 2359296;
  const size_t RWT_F = 10 * 128 * 1152;
  const size_t SMALL_F = 40960 + 4096 + 256 + 131072 + 262144;
  const size_t fixed_f = WGP_F + 2 * PQ_F + U_F + RWT_F + SMALL_F;
  int chunk = 256;
  while (chunk > 8 && (fixed_f + (size_t)chunk * 104960) * 4 > ws_size) chunk >>= 1;

  __hip_bfloat16* wGp  = (__hip_bfloat16*)ws;
  __hip_bfloat16* hTgc = (__hip_bfloat16*)(ws + WGP_F);
  float* pq   = ws + WGP_F + (size_t)chunk * 104960;
  float* u    = pq + 2 * PQ_F;
  float* rwT  = u + U_F;
  float* vecs = rwT + RWT_F;
  float* h1   = vecs + 40960 + 4096 + 256;
  float* h2   = h1 + 131072;

  k_prep<<<dim3(3892), dim3(256), 0, stream>>>(pw, wGp, rw, rwT, x, c1w, c1b, hTgc);
  k_conv2<<<dim3(512), dim3(512), 0, stream>>>(hTgc, wGp, pq, 0);
  k_squash<<<dim3(256), dim3(256), 0, stream>>>(pq, pb, u);
  k_route<<<dim3(1280), dim3(512), 0, stream>>>(u, rwT, vecs);
  k_dec1<<<dim3(256), dim3(512), 0, stream>>>(vecs, w1, b1, out, h1);
  k_dec2<<<dim3(1024), dim3(128), 0, stream>>>(h1, w2, b2, h2);
  k_dec3<<<dim3(896), dim3(128), 0, stream>>>(h2, w3, b3, out + 2560);
}

// Round 16
// 732.328 us; speedup vs baseline: 1.1039x; 1.0234x over previous
//
#include <hip/hip_runtime.h>
#include <hip/hip_bf16.h>
#include <math.h>

// ---------------------------------------------------------------------------
// CapsNet forward. R16 = R15 + route load-width fix:
//  - rwT repacked as rwT2[o][c*4+dq][i][4d] (same bytes) so route's prior
//    loop issues 96 b128 loads/thread instead of 384 scalar dwords
//    (16 d-strided loads per (c,i) were the issue/latency bottleneck at
//    1 block/CU).  rrep branch emits the new layout with 1KB-contiguous
//    writes. Everything else identical to R15 (best: 749us).
// ---------------------------------------------------------------------------

typedef __attribute__((ext_vector_type(8))) short bf16x8;
typedef __attribute__((ext_vector_type(4))) float f32x4;

__device__ __forceinline__ void gl16(const void* g, void* l) {
  __builtin_amdgcn_global_load_lds((const __attribute__((address_space(1))) void*)g,
                                   (__attribute__((address_space(3))) void*)l,
                                   16, 0, 0);
}

// ==== k_prep: [0,2688) wrep | [2688,2868) rrep | [2868,3892) conv1 =========
__global__ __launch_bounds__(256) void k_prep(
    const float* __restrict__ pw, __hip_bfloat16* __restrict__ wGp,
    const float* __restrict__ rw, float* __restrict__ rwT,
    const float* __restrict__ x, const float* __restrict__ c1w,
    const float* __restrict__ c1b, __hip_bfloat16* __restrict__ hT) {
  __shared__ __attribute__((aligned(16))) char smem[44480];
  const int bid = blockIdx.x;
  const int t = threadIdx.x;
  if (bid < 2688) {                                 // ---- wrep ----
    const int s = bid >> 2, ocq = bid & 3;          // s in [0,672)
    const int ch = s / 21, tq = s - ch * 21;
    __hip_bfloat16* outp = wGp + ((size_t)s * 4 + ocq) * 4608;
    for (int e = t; e < 2048; e += 256) {
      const int ocl = e >> 5, k = e & 31;
      const int tapl = k >> 3, icl = k & 7;
      const int tap = tq * 4 + tapl, ic = ch * 8 + icl;
      const int oc = ocq * 64 + ocl;
      const float v = (tap < 81) ? pw[((size_t)oc * 256 + ic) * 81 + tap] : 0.f;
      const __hip_bfloat16 hi = __float2bfloat16(v);
      const __hip_bfloat16 lo = __float2bfloat16(v - __bfloat162float(hi));
      outp[ocl * 72 + k] = hi;
      outp[ocl * 72 + 32 + k] = lo;
    }
    for (int e = t; e < 512; e += 256) {
      const int ocl = e >> 3, j = e & 7;
      outp[ocl * 72 + 64 + j] = __float2bfloat16(0.f);
    }
  } else if (bid < 2868) {                          // ---- rrep ----
    // rw[o][i][c][d] -> rwT2[o][c*4+dq][i][4]  (d = dq*4+dl)
    float* tile = (float*)smem;                     // 64*129 floats (33KB)
    const int bb = bid - 2688;
    const int o = bb / 18, ig = bb % 18;
    for (int idx = t; idx < 64 * 128; idx += 256) {
      const int i = idx >> 7, cd = idx & 127;
      tile[i * 129 + cd] = rw[((size_t)o * 1152 + ig * 64 + i) * 128 + cd];
    }
    __syncthreads();
    const int il = t >> 2, dl = t & 3;              // 256 thr = 64 il x 4 dl
#pragma unroll 1
    for (int cdq = 0; cdq < 32; cdq++) {            // 1KB contiguous writes
      const int c = cdq >> 2, dq = cdq & 3;
      rwT[((size_t)(o * 32 + cdq) * 1152 + ig * 64 + il) * 4 + dl] =
          tile[il * 129 + c * 16 + dq * 4 + dl];
    }
  } else {                                          // ---- conv1 ----
    const int bb = bid - 2868;
    const int img = bb >> 2, ocq = bb & 3;          // 64 oc per block
    float* xs = (float*)smem;                       // 784 f
    float* ws = xs + 784;                           // 5184 f
    __hip_bfloat16* tile = (__hip_bfloat16*)(ws + 5184);  // 8*1288 bf16
    const float4* xg = (const float4*)(x + (size_t)img * 784);
    if (t < 196) ((float4*)xs)[t] = xg[t];
    const float4* wg = (const float4*)(c1w + (size_t)ocq * 64 * 81);
    for (int i = t; i < 1296; i += 256) ((float4*)ws)[i] = wg[i];
    __syncthreads();
    const int ocl = t & 63, rowg = t >> 6;          // wave = rowg
    const int oc = ocq * 64 + ocl;
    const int chl = ocl >> 3, icl = ocl & 7;
    const float bv = c1b[oc];
    __hip_bfloat16* hb = hT + ((size_t)img * 32 + ocq * 8) * 6560;
#pragma unroll 1
    for (int it = 0; it < 5; it++) {
      const int r = it * 4 + rowg;                  // y
      float acc[20];
#pragma unroll
      for (int p = 0; p < 20; p++) acc[p] = bv;
#pragma unroll
      for (int ky = 0; ky < 9; ky++) {
        float xr[28];
        const float* xrow = &xs[(r + ky) * 28];
#pragma unroll
        for (int q = 0; q < 7; q++) ((float4*)xr)[q] = ((const float4*)xrow)[q];
        float wr[9];
#pragma unroll
        for (int i = 0; i < 9; i++) wr[i] = ws[ocl * 81 + ky * 9 + i];
#pragma unroll
        for (int kx = 0; kx < 9; kx++)
#pragma unroll
          for (int p = 0; p < 20; p++)
            acc[p] = fmaf(wr[kx], xr[p + kx], acc[p]);
      }
#pragma unroll
      for (int p = 0; p < 20; p++) {                // p = x
        const float v = fmaxf(acc[p], 0.f);
        const __hip_bfloat16 hi = __float2bfloat16(v);
        const __hip_bfloat16 lo = __float2bfloat16(v - __bfloat162float(hi));
        tile[chl * 1288 + (p * 8 + rowg * 2) * 8 + icl] = hi;
        tile[chl * 1288 + (p * 8 + rowg * 2 + 1) * 8 + icl] = lo;
      }
      __syncthreads();
#pragma unroll
      for (int q = 0; q < 5; q++) {                 // 1280 16B chunks
        const int idx = q * 256 + t;
        const int c2 = idx / 160, rem = idx - c2 * 160;
        const int xx = rem >> 3, j = rem & 7;
        const float4 vdat = *(const float4*)&tile[c2 * 1288 + rem * 8];
        *(float4*)(hb + (size_t)c2 * 6560 + (size_t)(xx * 41 + it * 8 + j) * 8) = vdat;
      }
      __syncthreads();
    }
  }
}

// ====== conv2 MFMA (R13): pq[kq][img][px36][oc256] partial over 16 ch ======
#define HT_B 52480              // 3280 chunks x 16B  (4 img x 820)
#define PQ_F 2359296
__global__ __launch_bounds__(512) void k_conv2(
    const __hip_bfloat16* __restrict__ hTg,    // [chunk img][32ch][820ch][8]
    const __hip_bfloat16* __restrict__ wGp,    // [672][4ocq][4608B] (+1 pad step)
    float* __restrict__ pq, int c0) {
  __shared__ char hT[HT_B];
  const int bid = blockIdx.x;
  int ig, ocq, kq;
  if (gridDim.x == 512) {       // XCD swizzle: ocq sharers keep bid%8
    ig = (bid & 7) | (((bid >> 5) & 7) << 3);
    ocq = (bid >> 3) & 3;
    kq = bid >> 8;
  } else {
    ig = bid >> 3;
    ocq = (bid >> 1) & 3;
    kq = bid & 1;
  }
  const int t = threadIdx.x;
  const int w = t >> 6, lane = t & 63;
  const int lquad = lane >> 4, lrow = lane & 15;
  const int mhalf = w >> 2;
  const int nt = mhalf ? 4 : 5;
  const int mtb = mhalf ? 5 : 0;
  const int ocg = ocq * 64 + (w & 3) * 16 + lrow;
  int abase[5];
#pragma unroll
  for (int i = 0; i < 5; i++) {
    int m = (mtb + i) * 16 + lrow;
    if (i >= nt) m = 0;
    const int img = m / 36, px = m - img * 36;
    const int oy = px / 6, ox = px - oy * 6;
    abase[i] = img * 13120 + ox * 1312 + oy * 64;   // bytes in hT
  }
  f32x4 acc[5];
#pragma unroll
  for (int i = 0; i < 5; i++) acc[i] = (f32x4){0.f, 0.f, 0.f, 0.f};

  const char* hgc = (const char*)hTg;
  const char* wp = (const char*)wGp + ((size_t)(kq * 336) * 4 + ocq) * 4608 +
                   ((w & 3) * 16 + lrow) * 144 + lquad * 16;
  bf16x8 bh = *(const bf16x8*)wp;
  bf16x8 bl = *(const bf16x8*)(wp + 64);
  wp += 18432;
#pragma unroll 1
  for (int chl = 0; chl < 16; chl++) {
    const int ch = kq * 16 + chl;
    const char* hch = hgc + ((size_t)(ig * 128) + ch) * 13120;
#pragma unroll
    for (int rr = 0; rr < 6; rr++) {
      const int idx = t + rr * 512;
      const int j = idx / 820, r = idx - j * 820;
      gl16(hch + (size_t)j * 419840 + r * 16, hT + rr * 8192 + w * 1024);
    }
    if (t < 208) {
      const int idx = 3072 + t;
      const int j = idx / 820, r = idx - j * 820;
      gl16(hch + (size_t)j * 419840 + r * 16, hT + 49152 + w * 1024);
    }
    __syncthreads();
#pragma unroll 1
    for (int tq = 0; tq < 21; tq++) {
      const bf16x8 nh = *(const bf16x8*)wp;         // prefetch next step's W
      const bf16x8 nl = *(const bf16x8*)(wp + 64);
      wp += 18432;
      const int tt = tq * 4 + lquad;                // this quad's tap
      const int ky = tt / 9, kx = tt - ky * 9;
      const int toff = kx * 656 + ky * 32;          // (kx*41 + ky*2) chunks
      bf16x8 ah[5];
#pragma unroll
      for (int i = 0; i < 5; i++)
        ah[i] = *(const bf16x8*)(hT + abase[i] + toff);
#pragma unroll
      for (int i = 0; i < 5; i++)
        if (i < nt) acc[i] = __builtin_amdgcn_mfma_f32_16x16x32_bf16(ah[i], bh, acc[i], 0, 0, 0);
#pragma unroll
      for (int i = 0; i < 5; i++)
        if (i < nt) acc[i] = __builtin_amdgcn_mfma_f32_16x16x32_bf16(ah[i], bl, acc[i], 0, 0, 0);
      bf16x8 al[5];
#pragma unroll
      for (int i = 0; i < 5; i++)
        al[i] = *(const bf16x8*)(hT + abase[i] + toff + 16);
#pragma unroll
      for (int i = 0; i < 5; i++)
        if (i < nt) acc[i] = __builtin_amdgcn_mfma_f32_16x16x32_bf16(al[i], bh, acc[i], 0, 0, 0);
      bh = nh;
      bl = nl;
    }
    __syncthreads();                                // hT reuse fence
  }
  float* pblk = pq + (size_t)kq * PQ_F;
#pragma unroll
  for (int i = 0; i < 5; i++) {
    if (i < nt) {
#pragma unroll
      for (int r = 0; r < 4; r++) {
        const int m = (mtb + i) * 16 + lquad * 4 + r;   // D row = quad*4+reg
        const int img = m / 36, px = m - img * 36;
        pblk[((size_t)(c0 + ig * 4 + img) * 36 + px) * 256 + ocg] = acc[i][r];
      }
    }
  }
}

// ===== squash v2: block/b, LDS-staged coalesced ============================
__global__ __launch_bounds__(256) void k_squash(const float* __restrict__ pq,
                                                const float* __restrict__ bias,
                                                float* __restrict__ u) {
  const int b = blockIdx.x;
  __shared__ float ps[36 * 257];
  const int t = threadIdx.x;
  const float4* s0 = (const float4*)(pq + (size_t)b * 9216);
  const float4* s1 = (const float4*)(pq + (size_t)PQ_F + (size_t)b * 9216);
#pragma unroll
  for (int q = 0; q < 9; q++) {                     // 2304 float4, coalesced
    const int idx = q * 256 + t;
    const float4 a = s0[idx], c = s1[idx];
    const int px = idx >> 6, oc = (idx & 63) * 4;
    float* dst = &ps[px * 257 + oc];
    dst[0] = a.x + c.x; dst[1] = a.y + c.y;
    dst[2] = a.z + c.z; dst[3] = a.w + c.w;
  }
  __syncthreads();
#pragma unroll
  for (int rr = 0; rr < 5; rr++) {
    const int i = rr * 256 + t;
    if (i < 1152) {
      const int cp = i / 36, px = i - cp * 36;
      float s[8], sq = 0.f;
#pragma unroll
      for (int d = 0; d < 8; d++) {
        s[d] = ps[px * 257 + d * 32 + cp] + bias[d * 32 + cp];
        sq = fmaf(s[d], s[d], sq);
      }
      const float scale = sq / ((1.f + sq) * sqrtf(sq));
      float o[8];
#pragma unroll
      for (int d = 0; d < 8; d++) o[d] = s[d] * scale;
      float* ub = u + ((size_t)b * 1152 + i) * 8;
      ((float4*)ub)[0] = ((float4*)o)[0];
      ((float4*)ub)[1] = ((float4*)o)[1];
    }
  }
}

// ======================= routing by agreement ==============================
__device__ __forceinline__ float wsum(float v) {
#pragma unroll
  for (int o = 32; o > 0; o >>= 1) v += __shfl_xor(v, o, 64);
  return v;
}
__device__ __forceinline__ float wmaxr(float v) {
#pragma unroll
  for (int o = 32; o > 0; o >>= 1) v = fmaxf(v, __shfl_xor(v, o, 64));
  return v;
}

// route v6: 2 imgs per block, priors fp32 in LDS (144KB), rwT2 b128 loads.
__global__ __launch_bounds__(512) void k_route(const float* __restrict__ u,
                                               const float* __restrict__ rwT,
                                               float* __restrict__ vecs) {
  const int bid = blockIdx.x;
  int o, bp;
  if (bid < 1024) { o = bid & 7; bp = bid >> 3; }        // XCD k gets o=k
  else { const int ix = bid - 1024; o = 8 + (ix & 1); bp = ix >> 1; }
  const int b0 = bp * 2;
  __shared__ __attribute__((aligned(16))) float pri4[2][4608 * 4];  // 144KB
  __shared__ float red[2][8 * 17];
  __shared__ float redm[2][8];
  const int t = threadIdx.x;
  const int wave = t >> 6, lane = t & 63;
  const float* rwo = rwT + (size_t)(o * 32) * 4608;      // [cdq32][1152][4]
  const float* ub0 = u + (size_t)b0 * 9216;
  const float* ub1 = ub0 + 9216;
#pragma unroll
  for (int ci = 0; ci < 3; ci++) {
    const bool valid = (ci < 2) || (t < 128);
    const int i = valid ? (t + ci * 512) : 0;
    float uv0[8], uv1[8];
    *(float4*)&uv0[0] = *(const float4*)(ub0 + i * 8);
    *(float4*)&uv0[4] = *(const float4*)(ub0 + i * 8 + 4);
    *(float4*)&uv1[0] = *(const float4*)(ub1 + i * 8);
    *(float4*)&uv1[4] = *(const float4*)(ub1 + i * 8 + 4);
    float a0[16], a1[16];
#pragma unroll
    for (int d = 0; d < 16; d++) { a0[d] = 0.f; a1[d] = 0.f; }
#pragma unroll
    for (int c = 0; c < 8; c++) {
#pragma unroll
      for (int dq = 0; dq < 4; dq++) {
        const float4 wv = *(const float4*)(rwo + (size_t)(c * 4 + dq) * 4608 + i * 4);
        a0[dq * 4 + 0] = fmaf(uv0[c], wv.x, a0[dq * 4 + 0]);
        a0[dq * 4 + 1] = fmaf(uv0[c], wv.y, a0[dq * 4 + 1]);
        a0[dq * 4 + 2] = fmaf(uv0[c], wv.z, a0[dq * 4 + 2]);
        a0[dq * 4 + 3] = fmaf(uv0[c], wv.w, a0[dq * 4 + 3]);
        a1[dq * 4 + 0] = fmaf(uv1[c], wv.x, a1[dq * 4 + 0]);
        a1[dq * 4 + 1] = fmaf(uv1[c], wv.y, a1[dq * 4 + 1]);
        a1[dq * 4 + 2] = fmaf(uv1[c], wv.z, a1[dq * 4 + 2]);
        a1[dq * 4 + 3] = fmaf(uv1[c], wv.w, a1[dq * 4 + 3]);
      }
    }
    if (valid) {
#pragma unroll
      for (int q = 0; q < 4; q++) {
        *(float4*)&pri4[0][(q * 1152 + i) * 4] = *(float4*)&a0[q * 4];
        *(float4*)&pri4[1][(q * 1152 + i) * 4] = *(float4*)&a1[q * 4];
      }
    }
  }
  __syncthreads();
  float l0[3], l1[3];
#pragma unroll
  for (int ci = 0; ci < 3; ci++) {
    const float init = ((ci < 2) || (t < 128)) ? 0.f : -1e30f;
    l0[ci] = init; l1[ci] = init;
  }
  float v0[16], v1[16];
#pragma unroll 1
  for (int it = 0; it < 3; it++) {
    float m0 = wmaxr(fmaxf(fmaxf(l0[0], l0[1]), l0[2]));
    float m1 = wmaxr(fmaxf(fmaxf(l1[0], l1[1]), l1[2]));
    if (lane == 0) { redm[0][wave] = m0; redm[1][wave] = m1; }
    __syncthreads();
    m0 = redm[0][0]; m1 = redm[1][0];
#pragma unroll
    for (int wv2 = 1; wv2 < 8; wv2++) {
      m0 = fmaxf(m0, redm[0][wv2]);
      m1 = fmaxf(m1, redm[1][wv2]);
    }
    float Z0 = 0.f, Z1 = 0.f, S0[16], S1[16];
#pragma unroll
    for (int d = 0; d < 16; d++) { S0[d] = 0.f; S1[d] = 0.f; }
#pragma unroll
    for (int ci = 0; ci < 3; ci++) {
      const bool valid = (ci < 2) || (t < 128);
      const int i = valid ? (t + ci * 512) : 0;
      const float e0 = expf(l0[ci] - m0);
      const float e1 = expf(l1[ci] - m1);
      Z0 += e0; Z1 += e1;
#pragma unroll
      for (int q = 0; q < 4; q++) {
        const float4 p0 = *(const float4*)&pri4[0][(q * 1152 + i) * 4];
        const float4 p1 = *(const float4*)&pri4[1][(q * 1152 + i) * 4];
        S0[q * 4 + 0] = fmaf(e0, p0.x, S0[q * 4 + 0]);
        S0[q * 4 + 1] = fmaf(e0, p0.y, S0[q * 4 + 1]);
        S0[q * 4 + 2] = fmaf(e0, p0.z, S0[q * 4 + 2]);
        S0[q * 4 + 3] = fmaf(e0, p0.w, S0[q * 4 + 3]);
        S1[q * 4 + 0] = fmaf(e1, p1.x, S1[q * 4 + 0]);
        S1[q * 4 + 1] = fmaf(e1, p1.y, S1[q * 4 + 1]);
        S1[q * 4 + 2] = fmaf(e1, p1.z, S1[q * 4 + 2]);
        S1[q * 4 + 3] = fmaf(e1, p1.w, S1[q * 4 + 3]);
      }
    }
    Z0 = wsum(Z0); Z1 = wsum(Z1);
#pragma unroll
    for (int d = 0; d < 16; d++) { S0[d] = wsum(S0[d]); S1[d] = wsum(S1[d]); }
    __syncthreads();                                 // red reuse fence
    if (lane == 0) {
      red[0][wave * 17] = Z0; red[1][wave * 17] = Z1;
#pragma unroll
      for (int d = 0; d < 16; d++) {
        red[0][wave * 17 + 1 + d] = S0[d];
        red[1][wave * 17 + 1 + d] = S1[d];
      }
    }
    __syncthreads();
    float Zt0 = 0.f, Zt1 = 0.f;
#pragma unroll
    for (int wv2 = 0; wv2 < 8; wv2++) { Zt0 += red[0][wv2 * 17]; Zt1 += red[1][wv2 * 17]; }
    float sq0 = 0.f, sq1 = 0.f;
#pragma unroll
    for (int d = 0; d < 16; d++) {
      float sd0 = 0.f, sd1 = 0.f;
#pragma unroll
      for (int wv2 = 0; wv2 < 8; wv2++) {
        sd0 += red[0][wv2 * 17 + 1 + d];
        sd1 += red[1][wv2 * 17 + 1 + d];
      }
      sd0 /= Zt0; sd1 /= Zt1;
      v0[d] = sd0; v1[d] = sd1;
      sq0 = fmaf(sd0, sd0, sq0);
      sq1 = fmaf(sd1, sd1, sq1);
    }
    const float sc0 = sq0 / ((1.f + sq0) * sqrtf(sq0));
    const float sc1 = sq1 / ((1.f + sq1) * sqrtf(sq1));
#pragma unroll
    for (int d = 0; d < 16; d++) { v0[d] *= sc0; v1[d] *= sc1; }
    if (it < 2) {
#pragma unroll
      for (int ci = 0; ci < 3; ci++) {
        const bool valid = (ci < 2) || (t < 128);
        const int i = valid ? (t + ci * 512) : 0;
        float d0 = 0.f, d1 = 0.f;
#pragma unroll
        for (int q = 0; q < 4; q++) {
          const float4 p0 = *(const float4*)&pri4[0][(q * 1152 + i) * 4];
          const float4 p1 = *(const float4*)&pri4[1][(q * 1152 + i) * 4];
          d0 = fmaf(p0.x, v0[q * 4 + 0], d0); d0 = fmaf(p0.y, v0[q * 4 + 1], d0);
          d0 = fmaf(p0.z, v0[q * 4 + 2], d0); d0 = fmaf(p0.w, v0[q * 4 + 3], d0);
          d1 = fmaf(p1.x, v1[q * 4 + 0], d1); d1 = fmaf(p1.y, v1[q * 4 + 1], d1);
          d1 = fmaf(p1.z, v1[q * 4 + 2], d1); d1 = fmaf(p1.w, v1[q * 4 + 3], d1);
        }
        l0[ci] += d0; l1[ci] += d1;
      }
    }
  }
  if (t == 0) {
    float* vb0 = vecs + ((size_t)b0 * 10 + o) * 16;
    float* vb1 = vecs + ((size_t)(b0 + 1) * 10 + o) * 16;
#pragma unroll
    for (int d = 0; d < 16; d++) { vb0[d] = v0[d]; vb1[d] = v1[d]; }
  }
}

// ====== dec1 (cls fused): classes softmax/argmax + first decoder layer =====
__global__ __launch_bounds__(512) void k_dec1(const float* __restrict__ vecs,
                                              const float* __restrict__ w1,
                                              const float* __restrict__ b1,
                                              float* __restrict__ out,
                                              float* __restrict__ h1) {
  const int b = blockIdx.x, t = threadIdx.x;
  __shared__ float vbs[160];
  __shared__ float sv[16];
  __shared__ int ams;
  const float* vb = vecs + (size_t)b * 160;
  if (t < 160) vbs[t] = vb[t];                      // coalesced
  __syncthreads();
  if (t == 0) {
    float nrm[10];
#pragma unroll
    for (int o = 0; o < 10; o++) {
      float sq = 0.f;
#pragma unroll
      for (int d = 0; d < 16; d++) { const float xv = vbs[o * 16 + d]; sq = fmaf(xv, xv, sq); }
      nrm[o] = sqrtf(sq);
    }
    float m = nrm[0];
#pragma unroll
    for (int o = 1; o < 10; o++) m = fmaxf(m, nrm[o]);
    float e[10], Z = 0.f;
#pragma unroll
    for (int o = 0; o < 10; o++) { e[o] = expf(nrm[o] - m); Z += e[o]; }
    const float inv = 1.f / Z;
    int am = 0;
    float best = e[0] * inv;
#pragma unroll
    for (int o = 0; o < 10; o++) {
      const float c = e[o] * inv;
      out[(size_t)b * 10 + o] = c;
      if (o > 0 && c > best) { best = c; am = o; }  // strict >: first-max
    }
    ams = am;
  }
  __syncthreads();
  const int am2 = ams;
  if (t < 16) sv[t] = vbs[am2 * 16 + t];
  __syncthreads();
  const float* wrow = w1 + (size_t)am2 * 16 * 512;
  float acc = b1[t];
#pragma unroll
  for (int d = 0; d < 16; d++) acc = fmaf(sv[d], wrow[d * 512 + t], acc);
  h1[(size_t)b * 512 + t] = fmaxf(acc, 0.f);
}

// dec2 v2: 2 imgs x 128 n per block (grid 1024); w2 in 32-k LDS tiles.
__global__ __launch_bounds__(128) void k_dec2(const float* __restrict__ h1,
                                              const float* __restrict__ w2,
                                              const float* __restrict__ b2,
                                              float* __restrict__ h2) {
  const int nc = blockIdx.x >> 7, bg = blockIdx.x & 127;
  const int t = threadIdx.x;
  const int n = nc * 128 + t;
  const int bs = bg * 2;
  __shared__ float h1s[2 * 512];
  __shared__ float wts[32 * 128];
  {
    const float4* src = (const float4*)(h1 + (size_t)bs * 512);
    for (int i = t; i < 256; i += 128) ((float4*)h1s)[i] = src[i];
  }
  float acc[2];
  const float bb = b2[n];
  acc[0] = bb; acc[1] = bb;
#pragma unroll 1
  for (int kt = 0; kt < 16; kt++) {
    __syncthreads();
#pragma unroll
    for (int r = 0; r < 32; r++)
      wts[r * 128 + t] = w2[(size_t)(kt * 32 + r) * 1024 + n];
    __syncthreads();
#pragma unroll
    for (int k4 = 0; k4 < 8; k4++) {
      float wq[4];
#pragma unroll
      for (int q = 0; q < 4; q++) wq[q] = wts[(k4 * 4 + q) * 128 + t];
#pragma unroll
      for (int j = 0; j < 2; j++) {
        const float4 hv = *(const float4*)&h1s[j * 512 + kt * 32 + k4 * 4];
        acc[j] = fmaf(hv.x, wq[0], acc[j]);
        acc[j] = fmaf(hv.y, wq[1], acc[j]);
        acc[j] = fmaf(hv.z, wq[2], acc[j]);
        acc[j] = fmaf(hv.w, wq[3], acc[j]);
      }
    }
  }
#pragma unroll
  for (int j = 0; j < 2; j++) h2[(size_t)(bs + j) * 1024 + n] = fmaxf(acc[j], 0.f);
}

// dec3 v2: 2 imgs x 112 n per block (grid 896); w3 in 32-k LDS tiles.
__global__ __launch_bounds__(128) void k_dec3(const float* __restrict__ h2,
                                              const float* __restrict__ w3,
                                              const float* __restrict__ b3,
                                              float* __restrict__ out) {
  const int nc = blockIdx.x >> 7, bg = blockIdx.x & 127;
  const int t = threadIdx.x;
  const int bs = bg * 2;
  __shared__ float h2s[2 * 1024];
  __shared__ float wts[32 * 112];
  {
    const float4* src = (const float4*)(h2 + (size_t)bs * 1024);
    for (int i = t; i < 512; i += 128) ((float4*)h2s)[i] = src[i];
  }
  const int n = nc * 112 + (t < 112 ? t : 0);
  float acc[2];
  const float bb = b3[n];
  acc[0] = bb; acc[1] = bb;
#pragma unroll 1
  for (int kt = 0; kt < 32; kt++) {
    __syncthreads();
#pragma unroll
    for (int r = 0; r < 32; r++)
      if (t < 112) wts[r * 112 + t] = w3[(size_t)(kt * 32 + r) * 784 + n];
    __syncthreads();
    if (t < 112) {
#pragma unroll
      for (int k4 = 0; k4 < 8; k4++) {
        float wq[4];
#pragma unroll
        for (int q = 0; q < 4; q++) wq[q] = wts[(k4 * 4 + q) * 112 + t];
#pragma unroll
        for (int j = 0; j < 2; j++) {
          const float4 hv = *(const float4*)&h2s[j * 1024 + kt * 32 + k4 * 4];
          acc[j] = fmaf(hv.x, wq[0], acc[j]);
          acc[j] = fmaf(hv.y, wq[1], acc[j]);
          acc[j] = fmaf(hv.z, wq[2], acc[j]);
          acc[j] = fmaf(hv.w, wq[3], acc[j]);
        }
      }
    }
  }
  if (t < 112) {
#pragma unroll
    for (int j = 0; j < 2; j++)
      out[(size_t)(bs + j) * 784 + n] = 1.f / (1.f + expf(-acc[j]));
  }
}

// ============================= launcher ====================================
extern "C" void kernel_launch(void* const* d_in, const int* in_sizes, int n_in,
                              void* d_out, int out_size, void* d_ws, size_t ws_size,
                              hipStream_t stream) {
  const float* x   = (const float*)d_in[0];
  const float* c1w = (const float*)d_in[1];
  const float* c1b = (const float*)d_in[2];
  const float* pw  = (const float*)d_in[3];
  const float* pb  = (const float*)d_in[4];
  const float* rw  = (const float*)d_in[5];
  const float* w1  = (const float*)d_in[6];
  const float* b1  = (const float*)d_in[7];
  const float* w2  = (const float*)d_in[8];
  const float* b2  = (const float*)d_in[9];
  const float* w3  = (const float*)d_in[10];
  const float* b3  = (const float*)d_in[11];
  float* out = (float*)d_out;
  float* ws = (float*)d_ws;

  const size_t WGP_F = ((size_t)672 * 4 * 4608 + 18432) / 4;
  const size_t U_F = 2359296;
  const size_t RWT_F = 10 * 32 * 4608;                 // same bytes, new layout
  const size_t SMALL_F = 40960 + 4096 + 256 + 131072 + 262144;
  const size_t fixed_f = WGP_F + 2 * PQ_F + U_F + RWT_F + SMALL_F;
  int chunk = 256;
  while (chunk > 8 && (fixed_f + (size_t)chunk * 104960) * 4 > ws_size) chunk >>= 1;

  __hip_bfloat16* wGp  = (__hip_bfloat16*)ws;
  __hip_bfloat16* hTgc = (__hip_bfloat16*)(ws + WGP_F);
  float* pq   = ws + WGP_F + (size_t)chunk * 104960;
  float* u    = pq + 2 * PQ_F;
  float* rwT  = u + U_F;
  float* vecs = rwT + RWT_F;
  float* h1   = vecs + 40960 + 4096 + 256;
  float* h2   = h1 + 131072;

  k_prep<<<dim3(3892), dim3(256), 0, stream>>>(pw, wGp, rw, rwT, x, c1w, c1b, hTgc);
  k_conv2<<<dim3(512), dim3(512), 0, stream>>>(hTgc, wGp, pq, 0);
  k_squash<<<dim3(256), dim3(256), 0, stream>>>(pq, pb, u);
  k_route<<<dim3(1280), dim3(512), 0, stream>>>(u, rwT, vecs);
  k_dec1<<<dim3(256), dim3(512), 0, stream>>>(vecs, w1, b1, out, h1);
  k_dec2<<<dim3(1024), dim3(128), 0, stream>>>(h1, w2, b2, h2);
  k_dec3<<<dim3(896), dim3(128), 0, stream>>>(h2, w3, b3, out + 2560);
}